// Round 4
// baseline (101.034 us; speedup 1.0000x reference)
//
#include <hip/hip_runtime.h>
#include <math.h>

#define BATCH 512
#define G 128
#define D 256
#define BK 64
#define NCH (D / BK)   // 4 K-chunks
#define LR 72          // LDS row stride in bf16 elems (144 B)
#define HROWS 64       // R rows per block (batch split in half)

typedef __attribute__((ext_vector_type(8))) short short8;
typedef __attribute__((ext_vector_type(4))) float f32x4;

__device__ __forceinline__ unsigned int pack2bf16(float a, float b) {
    unsigned int ua = __float_as_uint(a);
    unsigned int ub = __float_as_uint(b);
    ua = (ua + 0x7FFFu + ((ua >> 16) & 1u)) >> 16;   // RNE
    ub = (ub + 0x7FFFu + ((ub >> 16) & 1u)) >> 16;
    return ua | (ub << 16);
}

// Grid 1024: block = (batch, half). Each block computes 64 rows x 128 cols of
// the similarity matrix. 4 waves, wave wv owns 16 rows (1 A-frag x 8 B-frags).
// fp32 -> bf16 staged in LDS, norms accumulated in fp32 during staging,
// mfma_16x16x32_bf16, fused softmax-CE; per-block CE partial -> d_ws.
__global__ __launch_bounds__(256, 4)
void contrastive_kernel(const float* __restrict__ rfeat,
                        const float* __restrict__ pfeat,
                        float* __restrict__ ce_part_out)
{
    const int blk = blockIdx.x;
    const int b = blk >> 1;
    const int h = blk & 1;
    const float* rb = rfeat + (size_t)b * (G * D) + (size_t)h * HROWS * D;
    const float* pb = pfeat + (size_t)b * (G * D);

    __shared__ unsigned short rs[HROWS * LR];
    __shared__ unsigned short ps[G * LR];
    __shared__ float inv_r[HROWS];
    __shared__ float inv_p[G];
    __shared__ float red[256];

    const int tid  = threadIdx.x;
    const int lane = tid & 63;
    const int wv   = tid >> 6;      // wave id 0..3
    const int lg   = lane >> 4;     // lane group 0..3
    const int lc   = lane & 15;     // col-in-fragment

    const int srow = tid >> 4;      // staging row base 0..15
    const int sc4  = tid & 15;      // staging float4 slot 0..15

    f32x4 acc[8];
#pragma unroll
    for (int nj = 0; nj < 8; ++nj) acc[nj] = (f32x4){0.f, 0.f, 0.f, 0.f};

    float nr[4], np_[8];
#pragma unroll
    for (int it = 0; it < 4; ++it) nr[it] = 0.f;
#pragma unroll
    for (int it = 0; it < 8; ++it) np_[it] = 0.f;

    for (int c = 0; c < NCH; ++c) {
        __syncthreads();   // protect LDS against previous-chunk readers
        // issue all 12 loads first for memory-level parallelism
        float4 rv[4], pv[8];
#pragma unroll
        for (int it = 0; it < 4; ++it)
            rv[it] = *reinterpret_cast<const float4*>(rb + (srow + 16 * it) * D + c * BK + sc4 * 4);
#pragma unroll
        for (int it = 0; it < 8; ++it)
            pv[it] = *reinterpret_cast<const float4*>(pb + (srow + 16 * it) * D + c * BK + sc4 * 4);

#pragma unroll
        for (int it = 0; it < 4; ++it) {
            const int row = srow + 16 * it;
            nr[it] += rv[it].x * rv[it].x + rv[it].y * rv[it].y
                    + rv[it].z * rv[it].z + rv[it].w * rv[it].w;
            *reinterpret_cast<uint2*>(&rs[row * LR + sc4 * 4]) =
                make_uint2(pack2bf16(rv[it].x, rv[it].y), pack2bf16(rv[it].z, rv[it].w));
        }
#pragma unroll
        for (int it = 0; it < 8; ++it) {
            const int row = srow + 16 * it;
            np_[it] += pv[it].x * pv[it].x + pv[it].y * pv[it].y
                     + pv[it].z * pv[it].z + pv[it].w * pv[it].w;
            *reinterpret_cast<uint2*>(&ps[row * LR + sc4 * 4]) =
                make_uint2(pack2bf16(pv[it].x, pv[it].y), pack2bf16(pv[it].z, pv[it].w));
        }
        __syncthreads();

        // 2 K-steps of 32; per wave 1 A-frag x 8 B-frags
#pragma unroll
        for (int ks = 0; ks < 2; ++ks) {
            const int kb = ks * 32 + lg * 8;
            short8 a0 = *reinterpret_cast<const short8*>(&rs[(wv * 16 + lc) * LR + kb]);
#pragma unroll
            for (int nj = 0; nj < 8; ++nj) {
                short8 b0 = *reinterpret_cast<const short8*>(&ps[(nj * 16 + lc) * LR + kb]);
                acc[nj] = __builtin_amdgcn_mfma_f32_16x16x32_bf16(a0, b0, acc[nj], 0, 0, 0);
            }
        }
    }

    // finalize norms: reduce over each 16-thread staging group
#pragma unroll
    for (int it = 0; it < 8; ++it) {
        float vp = np_[it];
        float vr = (it < 4) ? nr[it] : 0.f;
#pragma unroll
        for (int off = 1; off < 16; off <<= 1) {
            vp += __shfl_xor(vp, off);
            if (it < 4) vr += __shfl_xor(vr, off);
        }
        if (sc4 == 0) {
            inv_p[srow + 16 * it] = 1.0f / fmaxf(sqrtf(vp), 1e-12f);
            if (it < 4) inv_r[srow + 16 * it] = 1.0f / fmaxf(sqrtf(vr), 1e-12f);
        }
    }
    __syncthreads();

    float invp_r[8];
#pragma unroll
    for (int nj = 0; nj < 8; ++nj) invp_r[nj] = inv_p[nj * 16 + lc];

    // C/D layout: col = lane&15, row = lg*4 + reg. Wave rows: wv*16 + lg*4 + reg.
    const int njd = h * 4 + wv;                 // fragment holding the diagonal col
    float ce_part = 0.f;
#pragma unroll
    for (int reg = 0; reg < 4; ++reg) {
        const int rrow = lg * 4 + reg;          // row-in-frag
        const float invr_g = inv_r[wv * 16 + rrow] * 10.0f;  // fold 1/TEMPERATURE
        float s[8];
        float m = -3.0e38f;
#pragma unroll
        for (int nj = 0; nj < 8; ++nj) {
            s[nj] = acc[nj][reg] * invr_g * invp_r[nj];
            m = fmaxf(m, s[nj]);
        }
#pragma unroll
        for (int off = 1; off < 16; off <<= 1) m = fmaxf(m, __shfl_xor(m, off));
        float e = 0.f;
#pragma unroll
        for (int nj = 0; nj < 8; ++nj) e += __expf(s[nj] - m);
#pragma unroll
        for (int off = 1; off < 16; off <<= 1) e += __shfl_xor(e, off);
        if (lc == rrow)                         // lane holding the diagonal element
            ce_part += (m + __logf(e)) - s[njd];
    }

    red[tid] = ce_part;
    __syncthreads();
    for (int sN = 128; sN > 0; sN >>= 1) {
        if (tid < sN) red[tid] += red[tid + sN];
        __syncthreads();
    }
    if (tid == 0) ce_part_out[blk] = red[0];
}

// out = sum((preds-y)^2) + 0.1 * (1/BATCH) * (1/G) * sum_blocks ce_part
__global__ __launch_bounds__(256)
void final_kernel(const float* __restrict__ preds,
                  const float* __restrict__ y,
                  const float* __restrict__ ce_part,
                  float* __restrict__ out)
{
    __shared__ float red[256];
    const int tid = threadIdx.x;
    const float k = 0.1f / ((float)BATCH * (float)G);
    float acc = 0.f;
    for (int i = tid; i < 2 * BATCH; i += 256) {
        if (i < BATCH) {
            float d = preds[i] - y[i];
            acc += d * d;
        }
        acc += k * ce_part[i];
    }
    red[tid] = acc;
    __syncthreads();
    for (int sN = 128; sN > 0; sN >>= 1) {
        if (tid < sN) red[tid] += red[tid + sN];
        __syncthreads();
    }
    if (tid == 0) out[0] = red[0];
}

extern "C" void kernel_launch(void* const* d_in, const int* in_sizes, int n_in,
                              void* d_out, int out_size, void* d_ws, size_t ws_size,
                              hipStream_t stream) {
    const float* preds = (const float*)d_in[0];
    const float* yv    = (const float*)d_in[1];
    const float* rf    = (const float*)d_in[2];
    const float* pf    = (const float*)d_in[3];
    // d_in[4], d_in[5] (batch indices) are uniform+sorted -> implicit reshape; unused.
    float* ce  = (float*)d_ws;                // 1024 floats scratch (per-block CE partials)
    float* out = (float*)d_out;

    contrastive_kernel<<<2 * BATCH, 256, 0, stream>>>(rf, pf, ce);
    final_kernel<<<1, 256, 0, stream>>>(preds, yv, ce, out);
}

// Round 5
// 52.915 us; speedup vs baseline: 1.9094x; 1.9094x over previous
//
#include <hip/hip_runtime.h>
#include <math.h>

#define BATCH 512
#define G 128
#define D 256
#define BK 64
#define NCH (D / BK)   // 4 K-chunks
#define LR 72          // LDS row stride in bf16 elems (144 B)

typedef __attribute__((ext_vector_type(8))) short short8;
typedef __attribute__((ext_vector_type(4))) float f32x4;

__device__ __forceinline__ unsigned int pack2bf16(float a, float b) {
    unsigned int ua = __float_as_uint(a);
    unsigned int ub = __float_as_uint(b);
    ua = (ua + 0x7FFFu + ((ua >> 16) & 1u)) >> 16;   // RNE
    ub = (ub + 0x7FFFu + ((ub >> 16) & 1u)) >> 16;
    return ua | (ub << 16);
}

// One block per batch, 512 threads (8 waves); wave wv owns S rows
// [16*wv, 16*wv+16) x all 128 cols (8 B-frags). fp32 read from HBM once,
// bf16 into LDS, norms in fp32 during staging, mfma_16x16x32_bf16,
// fused softmax-CE. Chunk loop fully unrolled with ping-pong register
// prefetch (T14): chunk c+1 loads issue before chunk c's pack+MFMA.
__global__ __launch_bounds__(512, 4)
void contrastive_kernel(const float* __restrict__ rfeat,
                        const float* __restrict__ pfeat,
                        float* __restrict__ ce_out)
{
    const int b = blockIdx.x;
    const float* rb = rfeat + (size_t)b * (G * D);
    const float* pb = pfeat + (size_t)b * (G * D);

    __shared__ unsigned short rs[G * LR];
    __shared__ unsigned short ps[G * LR];
    __shared__ float inv_r[G];
    __shared__ float inv_p[G];
    __shared__ float red[512];

    const int tid  = threadIdx.x;
    const int lane = tid & 63;
    const int wv   = tid >> 6;      // wave id 0..7
    const int lg   = lane >> 4;     // lane group 0..3
    const int lc   = lane & 15;     // col-in-fragment

    const int srow = tid >> 4;      // staging row base 0..31
    const int sc4  = tid & 15;      // staging float4 slot 0..15

    f32x4 acc[8];
#pragma unroll
    for (int nj = 0; nj < 8; ++nj) acc[nj] = (f32x4){0.f, 0.f, 0.f, 0.f};

    float nr[4], np_[4];
#pragma unroll
    for (int it = 0; it < 4; ++it) { nr[it] = 0.f; np_[it] = 0.f; }

    // ping-pong prefetch buffers (static indexing via full unroll)
    float4 rv[2][4], pv[2][4];

    // prologue: issue chunk 0 loads
#pragma unroll
    for (int it = 0; it < 4; ++it) {
        rv[0][it] = *reinterpret_cast<const float4*>(rb + (srow + 32 * it) * D + sc4 * 4);
        pv[0][it] = *reinterpret_cast<const float4*>(pb + (srow + 32 * it) * D + sc4 * 4);
    }

#pragma unroll
    for (int c = 0; c < NCH; ++c) {
        const int cur = c & 1, nxt = cur ^ 1;
        __syncthreads();   // previous chunk's LDS readers done
        // issue next chunk's loads first — they fly during pack + MFMA
        if (c + 1 < NCH) {
#pragma unroll
            for (int it = 0; it < 4; ++it) {
                rv[nxt][it] = *reinterpret_cast<const float4*>(rb + (srow + 32 * it) * D + (c + 1) * BK + sc4 * 4);
                pv[nxt][it] = *reinterpret_cast<const float4*>(pb + (srow + 32 * it) * D + (c + 1) * BK + sc4 * 4);
            }
        }
        // pack current chunk into LDS + accumulate norms
#pragma unroll
        for (int it = 0; it < 4; ++it) {
            const int row = srow + 32 * it;
            const float4 r4 = rv[cur][it];
            const float4 p4 = pv[cur][it];
            nr[it]  += r4.x * r4.x + r4.y * r4.y + r4.z * r4.z + r4.w * r4.w;
            np_[it] += p4.x * p4.x + p4.y * p4.y + p4.z * p4.z + p4.w * p4.w;
            *reinterpret_cast<uint2*>(&rs[row * LR + sc4 * 4]) =
                make_uint2(pack2bf16(r4.x, r4.y), pack2bf16(r4.z, r4.w));
            *reinterpret_cast<uint2*>(&ps[row * LR + sc4 * 4]) =
                make_uint2(pack2bf16(p4.x, p4.y), pack2bf16(p4.z, p4.w));
        }
        __syncthreads();   // LDS writes visible

        // 2 K-steps of 32; per wave 1 A-frag x 8 B-frags
#pragma unroll
        for (int ks = 0; ks < 2; ++ks) {
            const int kb = ks * 32 + lg * 8;
            short8 a0 = *reinterpret_cast<const short8*>(&rs[(wv * 16 + lc) * LR + kb]);
#pragma unroll
            for (int nj = 0; nj < 8; ++nj) {
                short8 b0 = *reinterpret_cast<const short8*>(&ps[(nj * 16 + lc) * LR + kb]);
                acc[nj] = __builtin_amdgcn_mfma_f32_16x16x32_bf16(a0, b0, acc[nj], 0, 0, 0);
            }
        }
    }

    // finalize norms: reduce over each 16-thread staging group (in-wave)
#pragma unroll
    for (int it = 0; it < 4; ++it) {
        float vr = nr[it], vp = np_[it];
#pragma unroll
        for (int off = 1; off < 16; off <<= 1) {
            vr += __shfl_xor(vr, off);
            vp += __shfl_xor(vp, off);
        }
        if (sc4 == 0) {
            const int row = srow + 32 * it;
            inv_r[row] = 1.0f / fmaxf(sqrtf(vr), 1e-12f);
            inv_p[row] = 1.0f / fmaxf(sqrtf(vp), 1e-12f);
        }
    }
    __syncthreads();

    float invp_r[8];
#pragma unroll
    for (int nj = 0; nj < 8; ++nj) invp_r[nj] = inv_p[nj * 16 + lc];

    // C/D layout: col = lane&15, row = lg*4 + reg. Wave rows: wv*16 + lg*4 + reg.
    const int njd = wv;                         // fragment holding the diagonal col
    float ce_part = 0.f;
#pragma unroll
    for (int reg = 0; reg < 4; ++reg) {
        const int rrow = lg * 4 + reg;          // row-in-frag
        const float invr_g = inv_r[wv * 16 + rrow] * 10.0f;  // fold 1/TEMPERATURE
        float s[8];
        float m = -3.0e38f;
#pragma unroll
        for (int nj = 0; nj < 8; ++nj) {
            s[nj] = acc[nj][reg] * invr_g * invp_r[nj];
            m = fmaxf(m, s[nj]);
        }
#pragma unroll
        for (int off = 1; off < 16; off <<= 1) m = fmaxf(m, __shfl_xor(m, off));
        float e = 0.f;
#pragma unroll
        for (int nj = 0; nj < 8; ++nj) e += __expf(s[nj] - m);
#pragma unroll
        for (int off = 1; off < 16; off <<= 1) e += __shfl_xor(e, off);
        if (lc == rrow)                         // lane holding the diagonal element
            ce_part += (m + __logf(e)) - s[njd];
    }

    red[tid] = ce_part;
    __syncthreads();
    for (int sN = 256; sN > 0; sN >>= 1) {
        if (tid < sN) red[tid] += red[tid + sN];
        __syncthreads();
    }
    if (tid == 0) ce_out[b] = red[0] * (1.0f / 128.0f);
}

// out = sum((preds-y)^2) + (0.1/BATCH) * sum_b ce[b]
__global__ __launch_bounds__(256)
void final_kernel(const float* __restrict__ preds,
                  const float* __restrict__ y,
                  const float* __restrict__ ce,
                  float* __restrict__ out)
{
    __shared__ float red[256];
    const int tid = threadIdx.x;
    float acc = 0.f;
    for (int i = tid; i < BATCH; i += 256) {
        float d = preds[i] - y[i];
        acc += d * d + (0.1f / (float)BATCH) * ce[i];
    }
    red[tid] = acc;
    __syncthreads();
    for (int sN = 128; sN > 0; sN >>= 1) {
        if (tid < sN) red[tid] += red[tid + sN];
        __syncthreads();
    }
    if (tid == 0) out[0] = red[0];
}

extern "C" void kernel_launch(void* const* d_in, const int* in_sizes, int n_in,
                              void* d_out, int out_size, void* d_ws, size_t ws_size,
                              hipStream_t stream) {
    const float* preds = (const float*)d_in[0];
    const float* yv    = (const float*)d_in[1];
    const float* rf    = (const float*)d_in[2];
    const float* pf    = (const float*)d_in[3];
    // d_in[4], d_in[5] (batch indices) are uniform+sorted -> implicit reshape; unused.
    float* ce  = (float*)d_ws;                // 512 floats scratch
    float* out = (float*)d_out;

    contrastive_kernel<<<BATCH, 512, 0, stream>>>(rf, pf, ce);
    final_kernel<<<1, 256, 0, stream>>>(preds, yv, ce, out);
}

// Round 6
// 32.002 us; speedup vs baseline: 3.1571x; 1.6535x over previous
//
#include <hip/hip_runtime.h>
#include <math.h>

#define BATCH 512
#define G 128
#define D 256
#define LRP 264   // LDS row stride in bf16 (528 B)

typedef __attribute__((ext_vector_type(8))) short short8;
typedef __attribute__((ext_vector_type(4))) float f32x4;
typedef __attribute__((ext_vector_type(4))) int  i32x4;

__device__ __forceinline__ unsigned int pack2bf16(float a, float b) {
    unsigned int ua = __float_as_uint(a);
    unsigned int ub = __float_as_uint(b);
    ua = (ua + 0x7FFFu + ((ua >> 16) & 1u)) >> 16;   // RNE
    ub = (ub + 0x7FFFu + ((ub >> 16) & 1u)) >> 16;
    return ua | (ub << 16);
}

// One block per batch, 512 threads (8 waves). Wave wv owns S rows
// [16wv,16wv+16). R is loaded DIRECTLY from global into A-fragment registers
// (no LDS, no barrier); P is staged fp32->bf16 into LDS in two 64-row halves
// with the half-1 loads issued before half-0's MFMA block (register prefetch
// hidden under 32 MFMAs). 3 compute barriers total (R3 had 9).
__global__ __launch_bounds__(512, 4)
void contrastive_kernel(const float* __restrict__ rfeat,
                        const float* __restrict__ pfeat,
                        float* __restrict__ ce_out)
{
    const int b = blockIdx.x;
    const float* rb = rfeat + (size_t)b * (G * D);
    const float* pb = pfeat + (size_t)b * (G * D);

    __shared__ unsigned short ps[64 * LRP];   // one 64-row half of P (bf16)
    __shared__ float inv_r[G];
    __shared__ float inv_p[G];
    __shared__ float red[8];

    const int tid  = threadIdx.x;
    const int lane = tid & 63;
    const int wv   = tid >> 6;      // wave 0..7
    const int lg   = lane >> 4;     // k-slot group 0..3
    const int lc   = lane & 15;     // row/col-in-fragment

    const int srow = tid >> 4;      // staging row base 0..31
    const int sc4  = tid & 15;      // staging slot 0..15

    // ---- R: global -> A-fragments (8 x short8 = 32 VGPR), norms in fp32 ----
    // lane (lg,lc) covers row 16wv+lc, cols {ks*32+lg*8 .. +8} -> wave reads
    // 16 full 128B lines per ks (perfectly coalesced in 4-lane groups).
    short8 afr[8];
    float nrsum = 0.f;
    const float* rptr = rb + (wv * 16 + lc) * D + lg * 8;
#pragma unroll
    for (int ks = 0; ks < 8; ++ks) {
        float4 x0 = *reinterpret_cast<const float4*>(rptr + ks * 32);
        float4 x1 = *reinterpret_cast<const float4*>(rptr + ks * 32 + 4);
        nrsum += x0.x*x0.x + x0.y*x0.y + x0.z*x0.z + x0.w*x0.w
               + x1.x*x1.x + x1.y*x1.y + x1.z*x1.z + x1.w*x1.w;
        i32x4 pk = { (int)pack2bf16(x0.x, x0.y), (int)pack2bf16(x0.z, x0.w),
                     (int)pack2bf16(x1.x, x1.y), (int)pack2bf16(x1.z, x1.w) };
        union { i32x4 i; short8 s; } u; u.i = pk;
        afr[ks] = u.s;
    }
    // combine the 4 lg-groups -> full row norm on every lane
    nrsum += __shfl_xor(nrsum, 16);
    nrsum += __shfl_xor(nrsum, 32);
    if (lane < 16)   // lg==0 lanes: lc == lane
        inv_r[wv * 16 + lane] = 10.0f / fmaxf(sqrtf(nrsum), 1e-12f);  // 1/T folded

    // ---- P half 0: stage rows [0,64) ----
    float4 pv[2][4];
#pragma unroll
    for (int it = 0; it < 2; ++it)
#pragma unroll
        for (int j = 0; j < 4; ++j)
            pv[it][j] = *reinterpret_cast<const float4*>(pb + (srow + 32 * it) * D + (sc4 + 16 * j) * 4);
#pragma unroll
    for (int it = 0; it < 2; ++it) {
        const int row = srow + 32 * it;
        float s = 0.f;
#pragma unroll
        for (int j = 0; j < 4; ++j) {
            const float4 v = pv[it][j];
            s += v.x*v.x + v.y*v.y + v.z*v.z + v.w*v.w;
            *reinterpret_cast<uint2*>(&ps[row * LRP + (sc4 + 16 * j) * 4]) =
                make_uint2(pack2bf16(v.x, v.y), pack2bf16(v.z, v.w));
        }
#pragma unroll
        for (int off = 1; off < 16; off <<= 1) s += __shfl_xor(s, off);
        if (sc4 == 0) inv_p[row] = 1.0f / fmaxf(sqrtf(s), 1e-12f);
    }
    __syncthreads();                                   // barrier 1: half-0 ready

    // issue half-1 loads BEFORE the MFMA block -> latency hidden under MFMAs
    float4 qv[2][4];
#pragma unroll
    for (int it = 0; it < 2; ++it)
#pragma unroll
        for (int j = 0; j < 4; ++j)
            qv[it][j] = *reinterpret_cast<const float4*>(pb + (64 + srow + 32 * it) * D + (sc4 + 16 * j) * 4);

    f32x4 acc[8];
#pragma unroll
    for (int nj = 0; nj < 8; ++nj) acc[nj] = (f32x4){0.f, 0.f, 0.f, 0.f};

    // MFMA half 0: cols [0,64) -> acc[0..3]
#pragma unroll
    for (int ks = 0; ks < 8; ++ks) {
        const int kb = ks * 32 + lg * 8;
#pragma unroll
        for (int nj = 0; nj < 4; ++nj) {
            short8 bfr = *reinterpret_cast<const short8*>(&ps[(nj * 16 + lc) * LRP + kb]);
            acc[nj] = __builtin_amdgcn_mfma_f32_16x16x32_bf16(afr[ks], bfr, acc[nj], 0, 0, 0);
        }
    }
    __syncthreads();                                   // barrier 2: half-0 reads done

    // ---- P half 1: pack rows [64,128) into the same buffer ----
#pragma unroll
    for (int it = 0; it < 2; ++it) {
        const int row = srow + 32 * it;                // local row in buffer
        float s = 0.f;
#pragma unroll
        for (int j = 0; j < 4; ++j) {
            const float4 v = qv[it][j];
            s += v.x*v.x + v.y*v.y + v.z*v.z + v.w*v.w;
            *reinterpret_cast<uint2*>(&ps[row * LRP + (sc4 + 16 * j) * 4]) =
                make_uint2(pack2bf16(v.x, v.y), pack2bf16(v.z, v.w));
        }
#pragma unroll
        for (int off = 1; off < 16; off <<= 1) s += __shfl_xor(s, off);
        if (sc4 == 0) inv_p[64 + row] = 1.0f / fmaxf(sqrtf(s), 1e-12f);
    }
    __syncthreads();                                   // barrier 3: half-1 ready

    // MFMA half 1: cols [64,128) -> acc[4..7]
#pragma unroll
    for (int ks = 0; ks < 8; ++ks) {
        const int kb = ks * 32 + lg * 8;
#pragma unroll
        for (int nj = 0; nj < 4; ++nj) {
            short8 bfr = *reinterpret_cast<const short8*>(&ps[(nj * 16 + lc) * LRP + kb]);
            acc[4 + nj] = __builtin_amdgcn_mfma_f32_16x16x32_bf16(afr[ks], bfr, acc[4 + nj], 0, 0, 0);
        }
    }

    // ---- fused softmax-CE ----
    float invp_r[8];
#pragma unroll
    for (int nj = 0; nj < 8; ++nj) invp_r[nj] = inv_p[nj * 16 + lc];

    // C/D layout: col = lane&15 (frag nj), row = lg*4+reg. Wave rows: 16wv+lg*4+reg.
    const int njd = wv;                                // fragment holding diag cols
    float ce_part = 0.f;
#pragma unroll
    for (int reg = 0; reg < 4; ++reg) {
        const int rrow = lg * 4 + reg;
        const float invr_g = inv_r[wv * 16 + rrow];    // already x10
        float s[8];
        float m = -3.0e38f;
#pragma unroll
        for (int nj = 0; nj < 8; ++nj) {
            s[nj] = acc[nj][reg] * invr_g * invp_r[nj];
            m = fmaxf(m, s[nj]);
        }
#pragma unroll
        for (int off = 1; off < 16; off <<= 1) m = fmaxf(m, __shfl_xor(m, off));
        float e = 0.f;
#pragma unroll
        for (int nj = 0; nj < 8; ++nj) e += __expf(s[nj] - m);
#pragma unroll
        for (int off = 1; off < 16; off <<= 1) e += __shfl_xor(e, off);
        if (lc == rrow)
            ce_part += (m + __logf(e)) - s[njd];
    }

    // wave-level reduce, then tiny cross-wave combine
#pragma unroll
    for (int off = 1; off < 64; off <<= 1) ce_part += __shfl_xor(ce_part, off);
    if (lane == 0) red[wv] = ce_part;
    __syncthreads();
    if (tid == 0) {
        float t = 0.f;
#pragma unroll
        for (int i = 0; i < 8; ++i) t += red[i];
        ce_out[b] = t * (1.0f / 128.0f);
    }
}

// out = sum((preds-y)^2) + (0.1/BATCH) * sum_b ce[b]
__global__ __launch_bounds__(256)
void final_kernel(const float* __restrict__ preds,
                  const float* __restrict__ y,
                  const float* __restrict__ ce,
                  float* __restrict__ out)
{
    __shared__ float red[256];
    const int tid = threadIdx.x;
    float acc = 0.f;
    for (int i = tid; i < BATCH; i += 256) {
        float d = preds[i] - y[i];
        acc += d * d + (0.1f / (float)BATCH) * ce[i];
    }
    red[tid] = acc;
    __syncthreads();
    for (int sN = 128; sN > 0; sN >>= 1) {
        if (tid < sN) red[tid] += red[tid + sN];
        __syncthreads();
    }
    if (tid == 0) out[0] = red[0];
}

extern "C" void kernel_launch(void* const* d_in, const int* in_sizes, int n_in,
                              void* d_out, int out_size, void* d_ws, size_t ws_size,
                              hipStream_t stream) {
    const float* preds = (const float*)d_in[0];
    const float* yv    = (const float*)d_in[1];
    const float* rf    = (const float*)d_in[2];
    const float* pf    = (const float*)d_in[3];
    // d_in[4], d_in[5] (batch indices) are uniform+sorted -> implicit reshape; unused.
    float* ce  = (float*)d_ws;                // 512 floats scratch
    float* out = (float*)d_out;

    contrastive_kernel<<<BATCH, 512, 0, stream>>>(rf, pf, ce);
    final_kernel<<<1, 256, 0, stream>>>(preds, yv, ce, out);
}